// Round 6
// baseline (4750.432 us; speedup 1.0000x reference)
//
#include <hip/hip_runtime.h>

#define L_SEQ 513
#define DM 768
#define DI 1536
#define DSTATE 16
#define DTRANK 48
#define NCLS 527
#define DEPTH 24
#define NC 32     // time chunks for parallel scan
#define CLEN 17   // ceil(513/32)
#define SKI 3     // split-K for in_proj (768 = 3*256)
#define SKO 8     // split-K for out_proj (1536 = 8*192)

typedef unsigned short u16;
typedef __bf16 bf16x8 __attribute__((ext_vector_type(8)));
typedef float f32x4 __attribute__((ext_vector_type(4)));

#define MFMA_BF16(A, B, C) __builtin_amdgcn_mfma_f32_16x16x32_bf16(A, B, C, 0, 0, 0)

__device__ inline u16 f2bf(float x) {
  unsigned u = __float_as_uint(x);
  return (u16)((u + 0x7FFFu + ((u >> 16) & 1u)) >> 16);
}
__device__ inline float bf2f(u16 h) { return __uint_as_float((unsigned)h << 16); }
__device__ inline void split2(float v, u16& h, u16& l) {
  h = f2bf(v);
  l = f2bf(v - bf2f(h));
}
// LDS offset with XOR swizzle: row of 32 u16 (4 groups of 8)
__device__ __forceinline__ int lofs(int row, int g) {
  int swz = (row & 3) ^ ((row >> 2) & 3);
  return row * 32 + ((g ^ swz) << 3);
}

// ---------------- weight fp32 -> bf16 hi/lo splitter ----------------
__global__ void wconvert_kernel(const float* __restrict__ src,
                                u16* __restrict__ hi, u16* __restrict__ lo,
                                long n4) {
  long i = (long)blockIdx.x * 256 + threadIdx.x;
  long stride = (long)gridDim.x * 256;
  for (; i < n4; i += stride) {
    float4 v = ((const float4*)src)[i];
    ushort4 h, l;
    split2(v.x, h.x, l.x);
    split2(v.y, h.y, l.y);
    split2(v.z, h.z, l.z);
    split2(v.w, h.w, l.w);
    ((ushort4*)hi)[i] = h;
    ((ushort4*)lo)[i] = l;
  }
}

// ---------------- patch embed + cls insert + pos add ----------------
__global__ void patch_embed_kernel(const float* __restrict__ x,
                                   const float* __restrict__ pw,
                                   const float* __restrict__ pb,
                                   const float* __restrict__ cls,
                                   const float* __restrict__ pos,
                                   float* __restrict__ hidden,
                                   float* __restrict__ residual) {
  int c = blockIdx.x * 256 + threadIdx.x;
  int s = blockIdx.y;
  if (c >= DM) return;
  float val;
  if (s == 256) {
    val = cls[c];
  } else {
    int p = s - (s > 256 ? 1 : 0);
    int gy = p >> 6, gx = p & 63;
    const float* xp = x + gy * 16 * 1024 + gx * 16;
    const float* wp = pw + c * 256;
    float acc = pb[c];
#pragma unroll 4
    for (int ky = 0; ky < 16; ++ky)
#pragma unroll
      for (int kx = 0; kx < 16; ++kx)
        acc += xp[ky * 1024 + kx] * wp[ky * 16 + kx];
    val = acc;
  }
  long idx = (long)s * DM + c;
  hidden[idx] = val + pos[idx];
  residual[idx] = 0.f;
}

// ---- residual += sum(hidden partials); hn = rmsnorm(residual)*w -> bf16 hi/lo ----
__global__ void rmsnorm_kernel(const float* __restrict__ hp, int nparts, long pstr,
                               float* __restrict__ residual,
                               u16* __restrict__ hnh, u16* __restrict__ hnl,
                               const float* __restrict__ w) {
  int t = blockIdx.x;
  float* rrow = residual + (long)t * DM;
  int tid = threadIdx.x;  // 256, DM = 3*256
  float vals[3];
  float ss = 0.f;
#pragma unroll
  for (int i = 0; i < 3; ++i) {
    int c = tid + i * 256;
    float v = rrow[c];
    for (int p = 0; p < nparts; ++p) v += hp[(long)p * pstr + (long)t * DM + c];
    vals[i] = v;
    rrow[c] = v;
    ss += v * v;
  }
#pragma unroll
  for (int o = 32; o; o >>= 1) ss += __shfl_down(ss, o, 64);
  __shared__ float sacc[4];
  if ((tid & 63) == 0) sacc[tid >> 6] = ss;
  __syncthreads();
  float tot = sacc[0] + sacc[1] + sacc[2] + sacc[3];
  float rs = rsqrtf(tot / (float)DM + 1e-5f);
#pragma unroll
  for (int i = 0; i < 3; ++i) {
    int c = tid + i * 256;
    float y = vals[i] * rs * w[c];
    u16 h, l;
    split2(y, h, l);
    hnh[(long)t * DM + c] = h;
    hnl[(long)t * DM + c] = l;
  }
}

// ---------------- 128x128 bf16 hi/lo MFMA GEMM, optional grid split-K ----------------
// AMODE 0: A given as pre-split hi/lo (u16). AMODE 1: A = 0.5*(A0+A1), fp32, split on the fly.
// C[m][n] = sum_k A[m][k]*B[n][k]; C = Ah*Bh + Ah*Bl + Al*Bh (fp32-accurate).
template <int AMODE>
__global__ __launch_bounds__(256) void gemm128(
    const void* __restrict__ A0, const void* __restrict__ A1,
    const u16* __restrict__ Bh, const u16* __restrict__ Bl,
    float* __restrict__ C,
    int M, int N, int K, int lda, int ldb, int ldc,
    long sA, long sB, long sC, int NSK, int Kb, long sP) {
  int z = blockIdx.z;
  int batch = z / NSK, sk = z - batch * NSK;
  const u16* Ahb = nullptr;
  const u16* Alb = nullptr;
  const float* Af = nullptr;
  const float* Ag = nullptr;
  if (AMODE == 0) {
    Ahb = (const u16*)A0 + (long)batch * sA;
    Alb = (const u16*)A1 + (long)batch * sA;
  } else {
    Af = (const float*)A0 + (long)batch * sA;
    Ag = (const float*)A1 + (long)batch * sA;
  }
  const u16* Bhb = Bh + (long)batch * sB;
  const u16* Blb = Bl + (long)batch * sB;
  float* Cb = C + (long)batch * sC + (long)sk * sP;
  int ks0 = sk * Kb;
  int kend = min(ks0 + Kb, K);

  __shared__ u16 SA[2][2][128 * 32];
  __shared__ u16 SB[2][2][128 * 32];  // 64 KB total

  int tid = threadIdx.x;
  int m0 = blockIdx.y * 128, n0 = blockIdx.x * 128;

  int r0 = tid >> 2, g0 = tid & 3;
  int r1 = r0 + 64;
  int l0 = lofs(r0, g0), l1 = lofs(r1, g0);
  long aoff0 = (long)(m0 + r0) * lda, aoff1 = (long)(m0 + r1) * lda;
  long boff0 = (long)(n0 + r0) * ldb, boff1 = (long)(n0 + r1) * ldb;
  bool am0 = (m0 + r0) < M, am1 = (m0 + r1) < M;
  bool bm0 = (n0 + r0) < N, bm1 = (n0 + r1) < N;

  int lane = tid & 63, w = tid >> 6;
  int wr = w >> 1, wc = w & 1;
  int fr = lane & 15, kh = lane >> 4;
  int offA[4], offB[4];
#pragma unroll
  for (int i = 0; i < 4; ++i) {
    offA[i] = lofs(wr * 64 + i * 16 + fr, kh);
    offB[i] = lofs(wc * 64 + i * 16 + fr, kh);
  }

  uint4 a0h, a1h, a0l, a1l, b0h, b1h, b0l, b1l;
  auto loadA = [&](long rowoff, bool ok, int k_, uint4& hh, uint4& ll) {
    uint4 z4 = {0, 0, 0, 0};
    if (AMODE == 0) {
      hh = ok ? *(const uint4*)(Ahb + rowoff + k_) : z4;
      ll = ok ? *(const uint4*)(Alb + rowoff + k_) : z4;
    } else {
      if (!ok) { hh = z4; ll = z4; return; }
      float4 f0 = *(const float4*)(Af + rowoff + k_);
      float4 f1 = *(const float4*)(Af + rowoff + k_ + 4);
      float4 g0v = *(const float4*)(Ag + rowoff + k_);
      float4 g1v = *(const float4*)(Ag + rowoff + k_ + 4);
      u16 ha[8], la[8];
      split2(0.5f * (f0.x + g0v.x), ha[0], la[0]);
      split2(0.5f * (f0.y + g0v.y), ha[1], la[1]);
      split2(0.5f * (f0.z + g0v.z), ha[2], la[2]);
      split2(0.5f * (f0.w + g0v.w), ha[3], la[3]);
      split2(0.5f * (f1.x + g1v.x), ha[4], la[4]);
      split2(0.5f * (f1.y + g1v.y), ha[5], la[5]);
      split2(0.5f * (f1.z + g1v.z), ha[6], la[6]);
      split2(0.5f * (f1.w + g1v.w), ha[7], la[7]);
      hh = *(const uint4*)ha;
      ll = *(const uint4*)la;
    }
  };
  auto loadstep = [&](int kb) {
    int k_ = kb + g0 * 8;
    bool kk = (k_ + 8 <= kend);
    uint4 z4 = {0, 0, 0, 0};
    loadA(aoff0, kk && am0, k_, a0h, a0l);
    loadA(aoff1, kk && am1, k_, a1h, a1l);
    b0h = (kk && bm0) ? *(const uint4*)(Bhb + boff0 + k_) : z4;
    b1h = (kk && bm1) ? *(const uint4*)(Bhb + boff1 + k_) : z4;
    b0l = (kk && bm0) ? *(const uint4*)(Blb + boff0 + k_) : z4;
    b1l = (kk && bm1) ? *(const uint4*)(Blb + boff1 + k_) : z4;
  };
  auto writebuf = [&](int b) {
    *(uint4*)&SA[b][0][l0] = a0h;
    *(uint4*)&SA[b][0][l1] = a1h;
    *(uint4*)&SA[b][1][l0] = a0l;
    *(uint4*)&SA[b][1][l1] = a1l;
    *(uint4*)&SB[b][0][l0] = b0h;
    *(uint4*)&SB[b][0][l1] = b1h;
    *(uint4*)&SB[b][1][l0] = b0l;
    *(uint4*)&SB[b][1][l1] = b1l;
  };

  f32x4 acc[4][4] = {};
  int nst = (kend - ks0 + 31) >> 5;
  loadstep(ks0);
  writebuf(0);
  if (nst > 1) loadstep(ks0 + 32);
  __syncthreads();

  for (int s = 0; s < nst; ++s) {
    int b = s & 1;
    bf16x8 fah[4], fal[4], fbh[4], fbl[4];
#pragma unroll
    for (int i = 0; i < 4; ++i) {
      fah[i] = __builtin_bit_cast(bf16x8, *(const uint4*)&SA[b][0][offA[i]]);
      fal[i] = __builtin_bit_cast(bf16x8, *(const uint4*)&SA[b][1][offA[i]]);
      fbh[i] = __builtin_bit_cast(bf16x8, *(const uint4*)&SB[b][0][offB[i]]);
      fbl[i] = __builtin_bit_cast(bf16x8, *(const uint4*)&SB[b][1][offB[i]]);
    }
#pragma unroll
    for (int mi = 0; mi < 4; ++mi)
#pragma unroll
      for (int ni = 0; ni < 4; ++ni) {
        acc[mi][ni] = MFMA_BF16(fah[mi], fbh[ni], acc[mi][ni]);
        acc[mi][ni] = MFMA_BF16(fah[mi], fbl[ni], acc[mi][ni]);
        acc[mi][ni] = MFMA_BF16(fal[mi], fbh[ni], acc[mi][ni]);
      }
    if (s + 1 < nst) {
      writebuf(b ^ 1);
      if (s + 2 < nst) loadstep(ks0 + (s + 2) * 32);
    }
    __syncthreads();
  }

#pragma unroll
  for (int mi = 0; mi < 4; ++mi)
#pragma unroll
    for (int ni = 0; ni < 4; ++ni) {
      int n = n0 + wc * 64 + ni * 16 + fr;
      if (n >= N) continue;
#pragma unroll
      for (int r = 0; r < 4; ++r) {
        int m = m0 + wr * 64 + mi * 16 + kh * 4 + r;
        if (m >= M) continue;
        Cb[(long)m * ldc + n] = acc[mi][ni][r];
      }
    }
}

// -------- causal conv (sums SKI partials) + silu -> fp32 + bf16 hi/lo, float4 --------
__global__ void conv_silu_kernel(const float* __restrict__ xz_p,
                                 const float* __restrict__ cw,
                                 const float* __restrict__ cb,
                                 float* __restrict__ xc,
                                 u16* __restrict__ xch, u16* __restrict__ xcl) {
  const long PZ = (long)L_SEQ * 2 * DI;
  int dir = blockIdx.y;
  int idx = blockIdx.x * 256 + threadIdx.x;  // over L_SEQ * DI/4
  if (idx >= L_SEQ * (DI / 4)) return;
  int d4 = idx % (DI / 4);
  int t = idx / (DI / 4);
  int d = d4 * 4;
  float wv[4][4];
#pragma unroll
  for (int j = 0; j < 4; ++j) {
    float4 wr = *(const float4*)(cw + ((long)dir * DI + d + j) * 4);
    wv[j][0] = wr.x; wv[j][1] = wr.y; wv[j][2] = wr.z; wv[j][3] = wr.w;
  }
  float4 bv = *(const float4*)(cb + (long)dir * DI + d);
  float a0 = bv.x, a1 = bv.y, a2 = bv.z, a3 = bv.w;
#pragma unroll
  for (int k = 0; k < 4; ++k) {
    int tau = t + k - 3;
    if (tau >= 0) {
      int tsrc = dir ? (L_SEQ - 1 - tau) : tau;
      long o = (long)tsrc * (2 * DI) + d;
      float4 x0 = *(const float4*)(xz_p + o);
      float4 x1 = *(const float4*)(xz_p + o + PZ);
      float4 x2 = *(const float4*)(xz_p + o + 2 * PZ);
      a0 += wv[0][k] * (x0.x + x1.x + x2.x);
      a1 += wv[1][k] * (x0.y + x1.y + x2.y);
      a2 += wv[2][k] * (x0.z + x1.z + x2.z);
      a3 += wv[3][k] * (x0.w + x1.w + x2.w);
    }
  }
  float4 sv;
  sv.x = a0 / (1.f + __expf(-a0));
  sv.y = a1 / (1.f + __expf(-a1));
  sv.z = a2 / (1.f + __expf(-a2));
  sv.w = a3 / (1.f + __expf(-a3));
  long o = ((long)dir * L_SEQ + t) * DI + d;
  *(float4*)(xc + o) = sv;
  ushort4 h, l;
  split2(sv.x, h.x, l.x);
  split2(sv.y, h.y, l.y);
  split2(sv.z, h.z, l.z);
  split2(sv.w, h.w, l.w);
  *(ushort4*)(xch + o) = h;
  *(ushort4*)(xcl + o) = l;
}

// ---------------- fused scan: dt on the fly + pass1 + fixup + pass2 ----------------
// grid (DI/8, 2); block 256 = 8 d-channels x 32 chunks
__global__ __launch_bounds__(256) void scan_all(
    const float* __restrict__ xc,       // (2,L,DI)
    const float* __restrict__ dbl,      // (2,L,80): [0:48]=dt-rank, [48:64]=B, [64:80]=C
    const float* __restrict__ xz_p,     // SKI partials, z at [., DI+d]
    const float* __restrict__ dtw,      // (2,DI,48)
    const float* __restrict__ dtb,      // (2,DI)
    const float* __restrict__ A_log,    // (2,DI,16)
    const float* __restrict__ Dsk,      // (2,DI)
    float* __restrict__ y) {            // (2,L,DI) un-reversed
  const long PZ = (long)L_SEQ * 2 * DI;
  int dir = blockIdx.y;
  int d0 = blockIdx.x * 8;
  int tid = threadIdx.x;
  __shared__ float Q[8][NC][DSTATE];  // 16 KB
  __shared__ float Sv[8][NC];

  const float* xcp = xc + (long)dir * L_SEQ * DI;
  const float* dblp = dbl + (long)dir * L_SEQ * 80;

  int dl = tid & 7, c = tid >> 3;
  int d = d0 + dl;
  float negA[DSTATE];
#pragma unroll
  for (int n = 0; n < DSTATE; ++n)
    negA[n] = -__expf(A_log[((long)dir * DI + d) * DSTATE + n]);
  float4 dwr[12];
  {
    const float4* dwp = (const float4*)(dtw + ((long)dir * DI + d) * DTRANK);
#pragma unroll
    for (int q = 0; q < 12; ++q) dwr[q] = dwp[q];
  }
  float db_ = dtb[(long)dir * DI + d];

  int t0 = c * CLEN, t1 = min(t0 + CLEN, L_SEQ);

  // pass 1: chunk-local scan
  {
    float h[DSTATE];
#pragma unroll
    for (int n = 0; n < DSTATE; ++n) h[n] = 0.f;
    float S = 0.f;
    for (int t = t0; t < t1; ++t) {
      const float4* R = (const float4*)(dblp + (long)t * 80);
      float dot = db_;
#pragma unroll
      for (int q = 0; q < 12; ++q) {
        float4 r4 = R[q];
        dot += r4.x * dwr[q].x + r4.y * dwr[q].y + r4.z * dwr[q].z + r4.w * dwr[q].w;
      }
      float dt = (dot > 20.f) ? dot : log1pf(__expf(dot));
      float u = xcp[(long)t * DI + d];
      float du = dt * u;
      S += dt;
      float4 b0 = R[12], b1 = R[13], b2 = R[14], b3 = R[15];
      float Bv[DSTATE] = {b0.x, b0.y, b0.z, b0.w, b1.x, b1.y, b1.z, b1.w,
                          b2.x, b2.y, b2.z, b2.w, b3.x, b3.y, b3.z, b3.w};
#pragma unroll
      for (int n = 0; n < DSTATE; ++n)
        h[n] = h[n] * __expf(dt * negA[n]) + du * Bv[n];
    }
    Sv[dl][c] = S;
#pragma unroll
    for (int n = 0; n < DSTATE; ++n) Q[dl][c][n] = h[n];
  }
  __syncthreads();
  // fix-up: 128 threads (dl, n); Q becomes chunk-start states
  if (tid < 128) {
    int fdl = tid >> 4, n = tid & 15;
    int fd = d0 + fdl;
    float nA = -__expf(A_log[((long)dir * DI + fd) * DSTATE + n]);
    float h = 0.f;
    for (int cc = 0; cc < NC; ++cc) {
      float S = Sv[fdl][cc];
      float q = Q[fdl][cc][n];
      Q[fdl][cc][n] = h;
      h = h * __expf(nA * S) + q;
    }
  }
  __syncthreads();
  // pass 2: re-scan from chunk-start, emit gated y
  {
    float h[DSTATE];
#pragma unroll
    for (int n = 0; n < DSTATE; ++n) h[n] = Q[dl][c][n];
    float dskip = Dsk[(long)dir * DI + d];
    for (int t = t0; t < t1; ++t) {
      const float4* R = (const float4*)(dblp + (long)t * 80);
      float dot = db_;
#pragma unroll
      for (int q = 0; q < 12; ++q) {
        float4 r4 = R[q];
        dot += r4.x * dwr[q].x + r4.y * dwr[q].y + r4.z * dwr[q].z + r4.w * dwr[q].w;
      }
      float dt = (dot > 20.f) ? dot : log1pf(__expf(dot));
      float u = xcp[(long)t * DI + d];
      float du = dt * u;
      float4 b0 = R[12], b1 = R[13], b2 = R[14], b3 = R[15];
      float4 c0 = R[16], c1 = R[17], c2 = R[18], c3 = R[19];
      float Bv[DSTATE] = {b0.x, b0.y, b0.z, b0.w, b1.x, b1.y, b1.z, b1.w,
                          b2.x, b2.y, b2.z, b2.w, b3.x, b3.y, b3.z, b3.w};
      float Cv[DSTATE] = {c0.x, c0.y, c0.z, c0.w, c1.x, c1.y, c1.z, c1.w,
                          c2.x, c2.y, c2.z, c2.w, c3.x, c3.y, c3.z, c3.w};
      float acc = 0.f;
#pragma unroll
      for (int n = 0; n < DSTATE; ++n) {
        h[n] = h[n] * __expf(dt * negA[n]) + du * Bv[n];
        acc += h[n] * Cv[n];
      }
      int tsrc = dir ? (L_SEQ - 1 - t) : t;
      long zo = (long)tsrc * (2 * DI) + DI + d;
      float zv = xz_p[zo] + xz_p[zo + PZ] + xz_p[zo + 2 * PZ];
      float sz = zv / (1.f + __expf(-zv));
      y[((long)dir * L_SEQ + tsrc) * DI + d] = (acc + dskip * u) * sz;
    }
  }
}

// ---------------- final rmsnorm(token 256) + head (sums SKO partials) ----------------
__global__ void head_kernel(const float* __restrict__ residual,
                            const float* __restrict__ hp, long pstr,
                            const float* __restrict__ nfw,
                            const float* __restrict__ hw,
                            const float* __restrict__ hb,
                            float* __restrict__ out) {
  int j = blockIdx.x;
  int tid = threadIdx.x;  // 256
  const float* r = residual + (long)256 * DM;
  float ss = 0.f, dp = 0.f;
#pragma unroll
  for (int i = 0; i < 3; ++i) {
    int c = tid + i * 256;
    float v = r[c];
    for (int p = 0; p < SKO; ++p) v += hp[(long)p * pstr + (long)256 * DM + c];
    ss += v * v;
    dp += v * nfw[c] * hw[(long)j * DM + c];
  }
#pragma unroll
  for (int o = 32; o; o >>= 1) {
    ss += __shfl_down(ss, o, 64);
    dp += __shfl_down(dp, o, 64);
  }
  __shared__ float s1[4], s2[4];
  if ((tid & 63) == 0) {
    s1[tid >> 6] = ss;
    s2[tid >> 6] = dp;
  }
  __syncthreads();
  if (tid == 0) {
    float tot = s1[0] + s1[1] + s1[2] + s1[3];
    float d = s2[0] + s2[1] + s2[2] + s2[3];
    out[j] = d * rsqrtf(tot / (float)DM + 1e-5f) + hb[j];
  }
}

extern "C" void kernel_launch(void* const* d_in, const int* in_sizes, int n_in,
                              void* d_out, int out_size, void* d_ws, size_t ws_size,
                              hipStream_t stream) {
  const float* x        = (const float*)d_in[0];
  const float* patch_w  = (const float*)d_in[1];
  const float* patch_b  = (const float*)d_in[2];
  const float* cls_tok  = (const float*)d_in[3];
  const float* pos_emb  = (const float*)d_in[4];
  const float* in_proj  = (const float*)d_in[5];
  const float* conv_w   = (const float*)d_in[6];
  const float* conv_b   = (const float*)d_in[7];
  const float* xproj_w  = (const float*)d_in[8];
  const float* dtproj_w = (const float*)d_in[9];
  const float* dtproj_b = (const float*)d_in[10];
  const float* A_log    = (const float*)d_in[11];
  const float* D_skip   = (const float*)d_in[12];
  const float* out_proj = (const float*)d_in[13];
  const float* norm_w   = (const float*)d_in[14];
  const float* norm_f_w = (const float*)d_in[15];
  const float* head_w   = (const float*)d_in[16];
  const float* head_b   = (const float*)d_in[17];
  float* out = (float*)d_out;

  const long PHN = (long)L_SEQ * DM;
  const long PZ  = (long)L_SEQ * 2 * DI;

  float* ws = (float*)d_ws;
  float* residual = ws; ws += PHN;
  float* xz_p     = ws; ws += SKI * PZ;
  float* xc       = ws; ws += (long)2 * L_SEQ * DI;
  float* dbl      = ws; ws += (long)2 * L_SEQ * 80;
  float* yb       = ws; ws += (long)2 * L_SEQ * DI;
  float* hid_p    = ws; ws += (long)SKO * PHN;

  u16* wsu = (u16*)ws;
  const long N_HN = PHN;
  const long N_XC = (long)2 * L_SEQ * DI;
  const long N_WI = (long)DEPTH * 2 * DI * DM;
  const long N_WX = (long)DEPTH * 2 * 80 * DI;
  const long N_WO = (long)DEPTH * DM * DI;
  u16* hn_h = wsu; wsu += N_HN;
  u16* hn_l = wsu; wsu += N_HN;
  u16* xc_h = wsu; wsu += N_XC;
  u16* xc_l = wsu; wsu += N_XC;
  u16* wi_h = wsu; wsu += N_WI;
  u16* wi_l = wsu; wsu += N_WI;
  u16* wx_h = wsu; wsu += N_WX;
  u16* wx_l = wsu; wsu += N_WX;
  u16* wo_h = wsu; wsu += N_WO;
  u16* wo_l = wsu; wsu += N_WO;

  wconvert_kernel<<<2048, 256, 0, stream>>>(in_proj,  wi_h, wi_l, N_WI / 4);
  wconvert_kernel<<<512,  256, 0, stream>>>(xproj_w,  wx_h, wx_l, N_WX / 4);
  wconvert_kernel<<<2048, 256, 0, stream>>>(out_proj, wo_h, wo_l, N_WO / 4);

  patch_embed_kernel<<<dim3(3, L_SEQ), 256, 0, stream>>>(
      x, patch_w, patch_b, cls_tok, pos_emb, hid_p, residual);

  for (int l = 0; l < DEPTH; ++l) {
    const u16* wih = wi_h + (long)l * 2 * DI * DM;
    const u16* wil = wi_l + (long)l * 2 * DI * DM;
    const u16* wxh = wx_h + (long)l * 2 * 80 * DI;
    const u16* wxl = wx_l + (long)l * 2 * 80 * DI;
    const u16* woh = wo_h + (long)l * DM * DI;
    const u16* wol = wo_l + (long)l * DM * DI;
    const float* cw  = conv_w   + (long)l * 2 * DI * 4;
    const float* cb  = conv_b   + (long)l * 2 * DI;
    const float* dw  = dtproj_w + (long)l * 2 * DI * DTRANK;
    const float* db  = dtproj_b + (long)l * 2 * DI;
    const float* Al  = A_log    + (long)l * 2 * DI * DSTATE;
    const float* Dk  = D_skip   + (long)l * 2 * DI;
    const float* nw  = norm_w   + (long)l * DM;

    rmsnorm_kernel<<<L_SEQ, 256, 0, stream>>>(
        hid_p, (l == 0) ? 1 : SKO, PHN, residual, hn_h, hn_l, nw);

    // xz partials(3): (513,3072) = hn @ ipw^T, split-K=3
    gemm128<0><<<dim3(24, 5, SKI), 256, 0, stream>>>(
        hn_h, hn_l, wih, wil, xz_p, L_SEQ, 2 * DI, DM, DM, DM, 2 * DI,
        0, 0, 0, SKI, DM / SKI, PZ);

    // conv + silu (sums 3 partials), float4
    conv_silu_kernel<<<dim3(770, 2), 256, 0, stream>>>(xz_p, cw, cb, xc, xc_h, xc_l);

    // dbl(513,80) = xc @ xw^T, batched over dir, full K
    gemm128<0><<<dim3(1, 5, 2), 256, 0, stream>>>(
        xc_h, xc_l, wxh, wxl, dbl, L_SEQ, 80, DI, DI, DI, 80,
        (long)L_SEQ * DI, (long)80 * DI, (long)L_SEQ * 80, 1, DI, 0);

    // fused scan (dt on the fly)
    scan_all<<<dim3(DI / 8, 2), 256, 0, stream>>>(
        xc, dbl, xz_p, dw, db, Al, Dk, yb);

    // hidden partials(8): (513,768) = 0.5*(yf+yb) @ opw^T, split-K=8, A fused
    gemm128<1><<<dim3(6, 5, SKO), 256, 0, stream>>>(
        yb, yb + (long)L_SEQ * DI, woh, wol, hid_p, L_SEQ, DM, DI, DI, DI, DM,
        0, 0, 0, SKO, DI / SKO, PHN);
  }

  head_kernel<<<NCLS, 256, 0, stream>>>(residual, hid_p, PHN,
                                        norm_f_w, head_w, head_b, out);
}